// Round 9
// baseline (4414.326 us; speedup 1.0000x reference)
//
#include <hip/hip_runtime.h>
#include <math.h>
#include <stdint.h>

#define BB     64
#define TENC   100
#define TDEC   50
#define LDIM   512
#define EE     512
#define HDIM   512
#define FIVEL  2560
#define RSTEPS 8
#define VOUT   30000
#define NB2    470     // 64-col partial chunks per logit row (470*64 = 30080)

typedef __attribute__((ext_vector_type(8))) short short8v;   // 8 x bf16
typedef __attribute__((ext_vector_type(4))) float floatx4;
typedef unsigned short ushort_t;

// ---------------- workspace offsets (float units) ----------------
static const size_t OFF_A        = 0;
static const size_t OFF_WIT_ENC  = 8192000;
static const size_t OFF_ENCX     = 8847360;    // ends 10,485,760
static const size_t OFF_LOGWT    = 0;
static const size_t OFF_DECH     = 7680000;    // ends 8,499,200
static const size_t OFF_DECPRE   = 8499200;    // ends 12,595,200
static const size_t OFF_ENC_HS   = 13107200;   // 1,638,400
static const size_t OFF_ENC_WHT  = 14745600;   // 655,360
static const size_t OFF_REVWC    = 15400960;   // 10,485,760 (dead post-review)
static const size_t OFF_PART     = 15400960;   // logit partials (aliases REVWC)
static const size_t OFF_DECWC    = 25886720;   // 1,310,720
static const size_t OFF_WIT_DEC  = 27197440;   // 655,360
static const size_t OFF_REVWT    = 27852800;   // 1,048,576
static const size_t OFF_DECWT    = 28901376;   // 131,072
static const size_t OFF_REVWH2AT = 29032448;   // 1,048,576
static const size_t OFF_DECWH2AT = 30081024;   // 131,072
static const size_t OFF_DECX     = 30212096;   // 819,200
static const size_t OFF_THOUGHT  = 31031296;   // 131,072
static const size_t OFF_TPROJ    = 31162368;   // 131,072
static const size_t OFF_HB0      = 31293440;   // 16,384
static const size_t OFF_HB1      = 31309824;   // 16,384
static const size_t OFF_ATTV     = 31326208;   // 16,384
static const size_t OFF_H0       = 31342592;   // 16,384
static const size_t OFF_C0       = 31358976;   // 4 x 32,768
static const size_t WS_TOTAL     = 31490048;   // ~126 MB (proven)

__device__ __forceinline__ float sigmoidf_(float x) { return 1.0f / (1.0f + __expf(-x)); }
__device__ __forceinline__ float tanh_fast(float x) { return 1.0f - 2.0f / (__expf(2.0f * x) + 1.0f); }
__device__ __forceinline__ unsigned short f2bf(float x) {
    unsigned u = __float_as_uint(x);
    u += 0x7FFFu + ((u >> 16) & 1u);
    return (unsigned short)(u >> 16);
}
__device__ __forceinline__ float bf2f(unsigned short h) {
    return __uint_as_float(((unsigned)h) << 16);
}

// ---------------------------------------------------------------------------
__global__ __launch_bounds__(128)
void gather_embed(const float* __restrict__ embed, const int* __restrict__ tok,
                  int T, ushort_t* __restrict__ X)
{
    int m = blockIdx.x, t = m / BB, b = m % BB;
    const float* src = embed + (size_t)tok[b * T + t] * EE;
    float4 v = *(const float4*)(src + threadIdx.x * 4);
    ushort4 o = { f2bf(v.x), f2bf(v.y), f2bf(v.z), f2bf(v.w) };
    *(ushort4*)(X + (size_t)m * EE + threadIdx.x * 4) = o;
}

// ---------------------------------------------------------------------------
// WT[z][n'][kofs+k] = bf16(W[z][k][n]).  gatetile=1 remaps output rows so
// block-local 16-col x 5-gate groups are contiguous:
//   n' = ((n%512)/16)*80 + (n/512)*16 + (n%16)      (N must be 2560)
// ---------------------------------------------------------------------------
__global__ __launch_bounds__(256)
void conv_transpose(const float* __restrict__ W, ushort_t* __restrict__ WT,
                    int N, int ldWT, int kofs, long Wz, long WTz, int gatetile)
{
    W  += (size_t)blockIdx.z * Wz;
    WT += (size_t)blockIdx.z * WTz;
    __shared__ float tile[32][33];
    int n0 = blockIdx.x * 32, k0 = blockIdx.y * 32;
    int tx = threadIdx.x & 31, ty = threadIdx.x >> 5;
    #pragma unroll
    for (int i = 0; i < 4; ++i) {
        int k = k0 + ty + i * 8, n = n0 + tx;
        tile[ty + i * 8][tx] = (n < N) ? W[(size_t)k * N + n] : 0.f;
    }
    __syncthreads();
    #pragma unroll
    for (int i = 0; i < 4; ++i) {
        int n = n0 + ty + i * 8, k = k0 + tx;
        if (n < N) {
            int np = gatetile ? (((n & 511) >> 4) * 80 + (n >> 9) * 16 + (n & 15)) : n;
            WT[(size_t)np * ldWT + kofs + k] = f2bf(tile[tx][ty + i * 8]);
        }
    }
}

// ---------------------------------------------------------------------------
// bf16 MFMA GEMM, bf16 out, LDS-staged coalesced epilogue (R8-proven).
// ---------------------------------------------------------------------------
__global__ __launch_bounds__(256)
void gemm_bf16(const ushort_t* __restrict__ A, const ushort_t* __restrict__ BT,
               const float* __restrict__ bias, ushort_t* __restrict__ Cb,
               int N, int K, long ldc)
{
    __shared__ ushort_t lds[2][128][32];
    __shared__ ushort_t ctile[128 * 128];
    const int tid  = threadIdx.x;
    const int wave = tid >> 6, lane = tid & 63;
    const int m0 = blockIdx.y * 128, n0 = blockIdx.x * 128;
    const int wr = wave >> 1, wc = wave & 1;

    floatx4 acc[4][4] = {};
    const int sr  = lane >> 2;
    const int scp = lane & 3;

    for (int k0 = 0; k0 < K; k0 += 32) {
        #pragma unroll
        for (int half = 0; half < 2; ++half) {
            int rbase = wave * 32 + half * 16;
            int r = rbase + sr;
            int c = scp ^ ((r >> 1) & 3);
            const ushort_t* ga = A + (size_t)(m0 + r) * K + k0 + c * 8;
            const ushort_t* gb = BT + (size_t)(n0 + r) * K + k0 + c * 8;
            __builtin_amdgcn_global_load_lds(
                (const __attribute__((address_space(1))) void*)ga,
                (__attribute__((address_space(3))) void*)&lds[0][rbase][0], 16, 0, 0);
            __builtin_amdgcn_global_load_lds(
                (const __attribute__((address_space(1))) void*)gb,
                (__attribute__((address_space(3))) void*)&lds[1][rbase][0], 16, 0, 0);
        }
        __syncthreads();

        short8v af[4], bv[4];
        #pragma unroll
        for (int i = 0; i < 4; ++i) {
            int ra = wr * 64 + i * 16 + (lane & 15);
            int ca = (lane >> 4) ^ ((ra >> 1) & 3);
            af[i] = *(const short8v*)&lds[0][ra][ca * 8];
            int rb = wc * 64 + i * 16 + (lane & 15);
            int cb = (lane >> 4) ^ ((rb >> 1) & 3);
            bv[i] = *(const short8v*)&lds[1][rb][cb * 8];
        }
        #pragma unroll
        for (int i = 0; i < 4; ++i)
            #pragma unroll
            for (int j = 0; j < 4; ++j)
                acc[i][j] = __builtin_amdgcn_mfma_f32_16x16x32_bf16(af[i], bv[j], acc[i][j], 0, 0, 0);
        __syncthreads();
    }

    const int crow0 = wr * 64 + (lane >> 4) * 4;
    const int ccol0 = wc * 64 + (lane & 15);
    #pragma unroll
    for (int i = 0; i < 4; ++i) {
        #pragma unroll
        for (int j = 0; j < 4; ++j) {
            int col = ccol0 + j * 16;
            float bval = bias ? bias[n0 + col] : 0.f;
            #pragma unroll
            for (int rr = 0; rr < 4; ++rr)
                ctile[(crow0 + i * 16 + rr) * 128 + col] = f2bf(acc[i][j][rr] + bval);
        }
    }
    __syncthreads();
    #pragma unroll
    for (int itc = 0; itc < 8; ++itc) {
        int chunk = itc * 256 + tid;
        int row = chunk >> 4, ch = chunk & 15;
        *(short8v*)(Cb + (size_t)(m0 + row) * ldc + n0 + ch * 8) =
            *(const short8v*)&ctile[row * 128 + ch * 8];
    }
}

// ---------------------------------------------------------------------------
// Logit GEMM (R8-proven): fused softmax partials + LDS-staged fp32 epilogue,
// row remap, full-cacheline stores.
// ---------------------------------------------------------------------------
__global__ __launch_bounds__(256)
void gemm_logit(const ushort_t* __restrict__ A, const ushort_t* __restrict__ BT,
                const float* __restrict__ bias, float* __restrict__ C,
                float2* __restrict__ part, int N, int K)
{
    __shared__ ushort_t lds[2][128][32];
    __shared__ float ctf[128 * 128];
    const int tid  = threadIdx.x;
    const int wave = tid >> 6, lane = tid & 63;
    const int m0 = blockIdx.y * 128, n0 = blockIdx.x * 128;
    const int wr = wave >> 1, wc = wave & 1;

    floatx4 acc[4][4] = {};
    const int sr  = lane >> 2;
    const int scp = lane & 3;

    for (int k0 = 0; k0 < K; k0 += 32) {
        #pragma unroll
        for (int half = 0; half < 2; ++half) {
            int rbase = wave * 32 + half * 16;
            int r = rbase + sr;
            int c = scp ^ ((r >> 1) & 3);
            const ushort_t* ga = A + (size_t)(m0 + r) * K + k0 + c * 8;
            int nr = n0 + r; if (nr >= N) nr = 0;
            const ushort_t* gb = BT + (size_t)nr * K + k0 + c * 8;
            __builtin_amdgcn_global_load_lds(
                (const __attribute__((address_space(1))) void*)ga,
                (__attribute__((address_space(3))) void*)&lds[0][rbase][0], 16, 0, 0);
            __builtin_amdgcn_global_load_lds(
                (const __attribute__((address_space(1))) void*)gb,
                (__attribute__((address_space(3))) void*)&lds[1][rbase][0], 16, 0, 0);
        }
        __syncthreads();

        short8v af[4], bv[4];
        #pragma unroll
        for (int i = 0; i < 4; ++i) {
            int ra = wr * 64 + i * 16 + (lane & 15);
            int ca = (lane >> 4) ^ ((ra >> 1) & 3);
            af[i] = *(const short8v*)&lds[0][ra][ca * 8];
            int rb = wc * 64 + i * 16 + (lane & 15);
            int cb = (lane >> 4) ^ ((rb >> 1) & 3);
            bv[i] = *(const short8v*)&lds[1][rb][cb * 8];
        }
        #pragma unroll
        for (int i = 0; i < 4; ++i)
            #pragma unroll
            for (int j = 0; j < 4; ++j)
                acc[i][j] = __builtin_amdgcn_mfma_f32_16x16x32_bf16(af[i], bv[j], acc[i][j], 0, 0, 0);
        __syncthreads();
    }

    const int cn = lane & 15, qq = lane >> 4;
    const int lcol0 = wc * 64 + cn;
    float bv[4]; bool valid[4];
    #pragma unroll
    for (int j = 0; j < 4; ++j) {
        int col = n0 + lcol0 + j * 16;
        valid[j] = col < N;
        bv[j] = valid[j] ? bias[col] : 0.f;
    }
    const int nb2 = blockIdx.x * 2 + wc;
    #pragma unroll
    for (int i = 0; i < 4; ++i) {
        #pragma unroll
        for (int rr = 0; rr < 4; ++rr) {
            int lrow = wr * 64 + qq * 4 + i * 16 + rr;
            int m = m0 + lrow;
            float v[4];
            #pragma unroll
            for (int j = 0; j < 4; ++j)
                v[j] = valid[j] ? acc[i][j][rr] + bv[j] : -3.0e38f;
            float mx = fmaxf(fmaxf(v[0], v[1]), fmaxf(v[2], v[3]));
            #pragma unroll
            for (int msk = 1; msk < 16; msk <<= 1) mx = fmaxf(mx, __shfl_xor(mx, msk));
            float sm = 0.f;
            #pragma unroll
            for (int j = 0; j < 4; ++j) if (valid[j]) sm += __expf(v[j] - mx);
            #pragma unroll
            for (int msk = 1; msk < 16; msk <<= 1) sm += __shfl_xor(sm, msk);
            if (cn == 0) part[(size_t)m * NB2 + nb2] = make_float2(mx, sm);
            #pragma unroll
            for (int j = 0; j < 4; ++j)
                ctf[lrow * 128 + lcol0 + j * 16] = v[j];
        }
    }
    __syncthreads();
    #pragma unroll
    for (int itc = 0; itc < 16; ++itc) {
        int chunk = itc * 256 + tid;
        int row = chunk >> 5, ch = chunk & 31;
        int col = n0 + ch * 4;
        if (col < N) {
            int m = m0 + row;
            int t = m >> 6, bb = m & 63;
            float* dst = C + ((size_t)bb * TDEC + t) * VOUT + col;
            if (col + 3 < N) {
                *(floatx4*)dst = *(const floatx4*)&ctf[row * 128 + ch * 4];
            } else {
                for (int e = 0; e < 4 && col + e < N; ++e)
                    dst[e] = ctf[row * 128 + ch * 4 + e];
            }
        }
    }
}

// ---------------------------------------------------------------------------
__global__ __launch_bounds__(256)
void logsm_sub(float* __restrict__ out, const float2* __restrict__ part)
{
    const int r = blockIdx.x;
    const int b = r / TDEC, t = r % TDEC;
    const int m = t * 64 + b;
    const int tid = threadIdx.x, wave = tid >> 6, lane = tid & 63;
    float M = -3.0e38f, S = 0.f;
    for (int i = tid; i < NB2; i += 256) {
        float2 p = part[(size_t)m * NB2 + i];
        float nm = fmaxf(M, p.x);
        S = S * __expf(M - nm) + p.y * __expf(p.x - nm);
        M = nm;
    }
    #pragma unroll
    for (int off = 32; off; off >>= 1) {
        float Mo = __shfl_xor(M, off), So = __shfl_xor(S, off);
        float nm = fmaxf(M, Mo);
        S = S * __expf(M - nm) + So * __expf(Mo - nm);
        M = nm;
    }
    __shared__ float ms[4], ss[4];
    if (lane == 0) { ms[wave] = M; ss[wave] = S; }
    __syncthreads();
    float M2 = fmaxf(fmaxf(ms[0], ms[1]), fmaxf(ms[2], ms[3]));
    float S2 = ss[0] * __expf(ms[0] - M2) + ss[1] * __expf(ms[1] - M2) +
               ss[2] * __expf(ms[2] - M2) + ss[3] * __expf(ms[3] - M2);
    float lse = M2 + __logf(S2);
    floatx4* row = (floatx4*)(out + (size_t)r * VOUT);
    for (int i = tid; i < VOUT / 4; i += 256) {
        floatx4 x = __builtin_nontemporal_load(row + i);
        x[0] -= lse; x[1] -= lse; x[2] -= lse; x[3] -= lse;
        __builtin_nontemporal_store(x, row + i);
    }
}

// ---------------------------------------------------------------------------
// Fused one-kernel LSTM step. 32 blocks x 256 thr.  Weights BTg are in the
// gate-tile layout: row n' = tile*80 + g*16 + i  <->  output col tile*16+i,
// gate g.  Block = tile: stages its 80 rows (80KB/segment) whole-K into LDS
// via global_load_lds, 80 MFMAs/wave from padded LDS (uniform 16B-group
// distribution -> no excess bank conflict), then the maxout-LSTM epilogue
// (R3-proven mapping) with no global s round-trip.
// ---------------------------------------------------------------------------
template<int NSEG>
__global__ __launch_bounds__(256)
void lstm_fused(const ushort_t* __restrict__ a0, const ushort_t* __restrict__ a1,
                const ushort_t* __restrict__ BTg, int ldBT,
                const ushort_t* __restrict__ pre,
                const float* __restrict__ b0, const float* __restrict__ b1,
                const float* __restrict__ c_in, float* __restrict__ c_out,
                ushort_t* __restrict__ h_out, ushort_t* __restrict__ h_copy)
{
    __shared__ ushort_t Bl[80][520];       // 81.25 KB, row stride 1040B (16B-aligned)
    const int tid = threadIdx.x, wave = tid >> 6, lane = tid & 63;
    const int q = lane >> 4, cn = lane & 15;
    const int c0 = blockIdx.x * 16;
    const int rowbase = blockIdx.x * 80;

    floatx4 acc[5] = {};
    const ushort_t* segs[2] = {a0, a1};

    #pragma unroll
    for (int seg = 0; seg < NSEG; ++seg) {
        if (seg) __syncthreads();          // protect Bl reuse
        for (int r = wave; r < 80; r += 4) {
            const ushort_t* src = BTg + (size_t)(rowbase + r) * ldBT + seg * 512 + lane * 8;
            __builtin_amdgcn_global_load_lds(
                (const __attribute__((address_space(1))) void*)src,
                (__attribute__((address_space(3))) void*)&Bl[r][0], 16, 0, 0);
        }
        __syncthreads();
        const ushort_t* Ap = segs[seg] + (size_t)(wave * 16 + cn) * 512 + q * 8;
        #pragma unroll
        for (int kt = 0; kt < 16; ++kt) {
            short8v af = *(const short8v*)(Ap + kt * 32);
            #pragma unroll
            for (int g = 0; g < 5; ++g) {
                short8v bf = *(const short8v*)&Bl[g * 16 + cn][kt * 32 + q * 8];
                acc[g] = __builtin_amdgcn_mfma_f32_16x16x32_bf16(af, bf, acc[g], 0, 0, 0);
            }
        }
    }

    // epilogue: rows m..m+3 (D row = q*4+rr within wave's 16), col c = c0+cn
    const int m = wave * 16 + q * 4;
    const int c = c0 + cn;
    float bias[5];
    #pragma unroll
    for (int g = 0; g < 5; ++g) {
        float v = b0[g * 512 + c];
        if (b1) v += b1[g * 512 + c];
        bias[g] = v;
    }
    #pragma unroll
    for (int rr = 0; rr < 4; ++rr) {
        int row = m + rr;
        float s[5];
        #pragma unroll
        for (int g = 0; g < 5; ++g) {
            s[g] = acc[g][rr] + bias[g];
            if (pre) s[g] += bf2f(pre[(size_t)row * FIVEL + g * 512 + c]);
        }
        float ig = sigmoidf_(s[0]), fg = sigmoidf_(s[1]), og = sigmoidf_(s[2]);
        float tt = fmaxf(s[3], s[4]);
        float c2 = fg * c_in[(size_t)row * 512 + c] + ig * tt;
        float h2 = og * tanh_fast(c2);
        c_out[(size_t)row * 512 + c] = c2;
        ushort_t hb_ = f2bf(h2);
        h_out[(size_t)row * 512 + c] = hb_;
        if (h_copy) h_copy[(size_t)row * 512 + c] = hb_;
    }
}

// ---------------------------------------------------------------------------
// Fused hproj(MFMA) + tanh-score + softmax + attv (R7/R8-proven). 64 blocks.
// ---------------------------------------------------------------------------
__global__ __launch_bounds__(256)
void attfuse2(const ushort_t* __restrict__ hprev,
              const ushort_t* __restrict__ projBase, long projLd,
              const ushort_t* __restrict__ feats,
              const ushort_t* __restrict__ W2aT, const float* __restrict__ b2a,
              const float* __restrict__ Watt, ushort_t* __restrict__ attv, int A)
{
    __shared__ float hp[512];
    __shared__ float ealpha[128];
    const int b = blockIdx.x;
    const int tid = threadIdx.x, wave = tid >> 6, lane = tid & 63;
    const int q = lane >> 4, cn = lane & 15;

    floatx4 acc[8] = {};
    {
        const ushort_t* Ap = hprev + (size_t)b * 512 + q * 8;
        const ushort_t* Bp = W2aT + (size_t)(wave * 128 + cn) * 512 + q * 8;
        #pragma unroll 2
        for (int kt = 0; kt < 16; ++kt) {
            short8v af = *(const short8v*)(Ap + kt * 32);
            #pragma unroll
            for (int t8 = 0; t8 < 8; ++t8) {
                short8v bf = *(const short8v*)(Bp + (size_t)t8 * 16 * 512 + kt * 32);
                acc[t8] = __builtin_amdgcn_mfma_f32_16x16x32_bf16(af, bf, acc[t8], 0, 0, 0);
            }
        }
    }
    if (q == 0) {
        #pragma unroll
        for (int t8 = 0; t8 < 8; ++t8) {
            int n = wave * 128 + t8 * 16 + cn;
            hp[n] = acc[t8][0] + b2a[n];
        }
    }
    __syncthreads();

    float hpr[8], war[8];
    {
        float4 w0 = *(const float4*)(Watt + lane * 8);
        float4 w1 = *(const float4*)(Watt + lane * 8 + 4);
        war[0] = w0.x; war[1] = w0.y; war[2] = w0.z; war[3] = w0.w;
        war[4] = w1.x; war[5] = w1.y; war[6] = w1.z; war[7] = w1.w;
        #pragma unroll
        for (int j = 0; j < 8; ++j) hpr[j] = hp[lane * 8 + j];
    }

    for (int a = wave; a < A; a += 4) {
        short8v pv = *(const short8v*)(projBase + ((size_t)a * 64 + b) * projLd + lane * 8);
        float e = 0.f;
        #pragma unroll
        for (int j = 0; j < 8; ++j)
            e += tanh_fast(bf2f((ushort_t)pv[j]) + hpr[j]) * war[j];
        #pragma unroll
        for (int off = 32; off; off >>= 1) e += __shfl_xor(e, off);
        if (lane == 0) ealpha[a] = e;
    }
    __syncthreads();
    if (wave == 0) {
        float v1 = (lane < A) ? ealpha[lane] : -3.0e38f;
        float v2 = (lane + 64 < A) ? ealpha[lane + 64] : -3.0e38f;
        float mm = fmaxf(v1, v2);
        #pragma unroll
        for (int off = 32; off; off >>= 1) mm = fmaxf(mm, __shfl_xor(mm, off));
        float x1 = (lane < A) ? __expf(v1 - mm) : 0.f;
        float x2 = (lane + 64 < A) ? __expf(v2 - mm) : 0.f;
        float ss = x1 + x2;
        #pragma unroll
        for (int off = 32; off; off >>= 1) ss += __shfl_xor(ss, off);
        float inv = 1.f / ss;
        if (lane < A) ealpha[lane] = x1 * inv;
        if (lane + 64 < A) ealpha[lane + 64] = x2 * inv;
    }
    __syncthreads();

    float s0 = 0.f, s1 = 0.f;
    for (int a = 0; a < A; ++a) {
        float al = ealpha[a];
        unsigned int u = *(const unsigned int*)(feats + ((size_t)a * 64 + b) * 512 + tid * 2);
        s0 += al * bf2f((ushort_t)(u & 0xffffu));
        s1 += al * bf2f((ushort_t)(u >> 16));
    }
    ushort2 o = { f2bf(s0), f2bf(s1) };
    *(ushort2*)(attv + (size_t)b * 512 + tid * 2) = o;
}

// ---------------------------------------------------------------------------
extern "C" void kernel_launch(void* const* d_in, const int* in_sizes, int n_in,
                              void* d_out_, int out_size, void* d_ws, size_t ws_size,
                              hipStream_t stream)
{
    const int*   code     = (const int*)  d_in[0];
    const int*   comment  = (const int*)  d_in[1];
    const float* embed    = (const float*)d_in[3];
    const float* enc_Wi   = (const float*)d_in[4];
    const float* enc_bi   = (const float*)d_in[5];
    const float* enc_Wh   = (const float*)d_in[6];
    const float* enc_bh   = (const float*)d_in[7];
    const float* rev_Wh   = (const float*)d_in[8];
    const float* rev_bh   = (const float*)d_in[9];
    const float* rev_Wa   = (const float*)d_in[10];
    const float* rev_ba   = (const float*)d_in[11];
    const float* rev_Wa2a = (const float*)d_in[12];
    const float* rev_ba2a = (const float*)d_in[13];
    const float* rev_Wh2a = (const float*)d_in[14];
    const float* rev_bh2a = (const float*)d_in[15];
    const float* rev_Watt = (const float*)d_in[16];
    const float* dec_Wi   = (const float*)d_in[18];
    const float* dec_bi   = (const float*)d_in[19];
    const float* dec_Wh   = (const float*)d_in[20];
    const float* dec_bh   = (const float*)d_in[21];
    const float* dec_Wa   = (const float*)d_in[22];
    const float* dec_ba   = (const float*)d_in[23];
    const float* dec_Wa2a = (const float*)d_in[24];
    const float* dec_ba2a = (const float*)d_in[25];
    const float* dec_Wh2a = (const float*)d_in[26];
    const float* dec_bh2a = (const float*)d_in[27];
    const float* dec_Watt = (const float*)d_in[28];
    const float* logit_W  = (const float*)d_in[30];
    const float* logit_b  = (const float*)d_in[31];
    float* out = (float*)d_out_;

    float* ws = (float*)d_ws;
    if (ws_size < WS_TOTAL * sizeof(float)) return;

    ushort_t* enc_pre_b = (ushort_t*)(ws + OFF_A);
    ushort_t* rev_projA = (ushort_t*)(ws + OFF_A);
    ushort_t* logit_WT  = (ushort_t*)(ws + OFF_LOGWT);
    ushort_t* dec_h_b   = (ushort_t*)(ws + OFF_DECH);
    ushort_t* dec_pre_b = (ushort_t*)(ws + OFF_DECPRE);
    ushort_t* WiT_enc   = (ushort_t*)(ws + OFF_WIT_ENC);
    ushort_t* enc_x_b   = (ushort_t*)(ws + OFF_ENCX);
    ushort_t* enc_hs_b  = (ushort_t*)(ws + OFF_ENC_HS);
    ushort_t* encWhT    = (ushort_t*)(ws + OFF_ENC_WHT);
    ushort_t* revWcomb  = (ushort_t*)(ws + OFF_REVWC);
    float2*   part      = (float2*)(ws + OFF_PART);
    ushort_t* decWcomb  = (ushort_t*)(ws + OFF_DECWC);
    ushort_t* WiT_dec   = (ushort_t*)(ws + OFF_WIT_DEC);
    ushort_t* revWT     = (ushort_t*)(ws + OFF_REVWT);
    ushort_t* decWT     = (ushort_t*)(ws + OFF_DECWT);
    ushort_t* revWh2aT  = (ushort_t*)(ws + OFF_REVWH2AT);
    ushort_t* decWh2aT  = (ushort_t*)(ws + OFF_DECWH2AT);
    ushort_t* dec_x_b   = (ushort_t*)(ws + OFF_DECX);
    ushort_t* thought_b = (ushort_t*)(ws + OFF_THOUGHT);
    ushort_t* tproj_b   = (ushort_t*)(ws + OFF_TPROJ);
    ushort_t* hb[2] = { (ushort_t*)(ws + OFF_HB0), (ushort_t*)(ws + OFF_HB1) };
    ushort_t* attv_b    = (ushort_t*)(ws + OFF_ATTV);
    ushort_t* h0_b      = (ushort_t*)(ws + OFF_H0);
    float* cbuf[4];
    for (int i = 0; i < 4; ++i) cbuf[i] = ws + OFF_C0 + (size_t)i * 32768;

    const dim3 blk(256);

    (void)hipMemsetAsync(cbuf[0], 0, (size_t)BB * LDIM * sizeof(float), stream);
    (void)hipMemsetAsync(h0_b, 0, (size_t)BB * LDIM * sizeof(ushort_t), stream);

    // ---- prep: gathers + weight transposes (step weights -> gate-tile) ----
    gather_embed<<<TENC * BB, 128, 0, stream>>>(embed, code, TENC, enc_x_b);
    gather_embed<<<TDEC * BB, 128, 0, stream>>>(embed, comment, TDEC, dec_x_b);
    conv_transpose<<<dim3(80, 16, 1), blk, 0, stream>>>(enc_Wi, WiT_enc, FIVEL, 512, 0, 0, 0, 0);
    conv_transpose<<<dim3(80, 16, 1), blk, 0, stream>>>(enc_Wh, encWhT, FIVEL, 512, 0, 0, 0, 1);
    conv_transpose<<<dim3(80, 16, 8), blk, 0, stream>>>(rev_Wh, revWcomb, FIVEL, 1024, 0,   1310720, 2621440, 1);
    conv_transpose<<<dim3(80, 16, 8), blk, 0, stream>>>(rev_Wa, revWcomb, FIVEL, 1024, 512, 1310720, 2621440, 1);
    conv_transpose<<<dim3(16, 16, 8), blk, 0, stream>>>(rev_Wa2a, revWT, 512, 512, 0,       262144, 262144, 0);
    conv_transpose<<<dim3(16, 16, 8), blk, 0, stream>>>(rev_Wh2a, revWh2aT, 512, 512, 0,    262144, 262144, 0);
    conv_transpose<<<dim3(80, 16, 1), blk, 0, stream>>>(dec_Wi, WiT_dec, FIVEL, 512, 0, 0, 0, 0);
    conv_transpose<<<dim3(80, 16, 1), blk, 0, stream>>>(dec_Wh, decWcomb, FIVEL, 1024, 0, 0, 0, 1);
    conv_transpose<<<dim3(80, 16, 1), blk, 0, stream>>>(dec_Wa, decWcomb, FIVEL, 1024, 512, 0, 0, 1);
    conv_transpose<<<dim3(16, 16, 1), blk, 0, stream>>>(dec_Wa2a, decWT, 512, 512, 0, 0, 0, 0);
    conv_transpose<<<dim3(16, 16, 1), blk, 0, stream>>>(dec_Wh2a, decWh2aT, 512, 512, 0, 0, 0, 0);

    // ---- hoisted encoder input GEMM: enc_pre = enc_x @ Wi + bi ----
    gemm_bf16<<<dim3(FIVEL / 128, TENC * BB / 128), blk, 0, stream>>>(
        enc_x_b, WiT_enc, enc_bi, enc_pre_b, FIVEL, EE, FIVEL);

    // ---- encoder scan (ONE kernel per step) ----
    for (int t = 0; t < TENC; ++t) {
        const ushort_t* hin = (t == 0) ? h0_b : enc_hs_b + (size_t)(t - 1) * 32768;
        lstm_fused<1><<<32, blk, 0, stream>>>(
            hin, nullptr, encWhT, 512,
            enc_pre_b + (size_t)t * 163840,
            enc_bh, nullptr,
            cbuf[t & 1], cbuf[(t + 1) & 1],
            enc_hs_b + (size_t)t * 32768, nullptr);
    }
    const ushort_t* h_enc = enc_hs_b + (size_t)(TENC - 1) * 32768;
    // c_enc = cbuf[0] (TENC = 100 even)

    // ---- hoisted review projections: rev_projA[m][r*512+n] ----
    gemm_bf16<<<dim3(32, 50), blk, 0, stream>>>(
        enc_hs_b, revWT, rev_ba2a, rev_projA, 4096, LDIM, 4096);

    // ---- review scan (2 kernels per step) ----
    const ushort_t* rh = h_enc;
    for (int r = 0; r < RSTEPS; ++r) {
        attfuse2<<<BB, blk, 0, stream>>>(
            rh, rev_projA + (size_t)r * 512, 4096, enc_hs_b,
            revWh2aT + (size_t)r * 262144, rev_bh2a + (size_t)r * 512,
            rev_Watt + (size_t)r * 512, attv_b, TENC);
        const float* ci = (r == 0) ? cbuf[0] : cbuf[2 + ((r - 1) & 1)];
        lstm_fused<2><<<32, blk, 0, stream>>>(
            rh, attv_b, revWcomb + (size_t)r * 2621440, 1024,
            nullptr, rev_bh + (size_t)r * FIVEL, rev_ba + (size_t)r * FIVEL,
            ci, cbuf[2 + (r & 1)],
            hb[r & 1], thought_b + (size_t)r * 32768);
        rh = hb[r & 1];
    }

    // ---- tproj + logit_WT + dec_pre (region A: rev_projA now dead) ----
    gemm_bf16<<<dim3(4, 4), blk, 0, stream>>>(
        thought_b, decWT, dec_ba2a, tproj_b, HDIM, LDIM, HDIM);
    conv_transpose<<<dim3((VOUT + 31) / 32, 16, 1), blk, 0, stream>>>(
        logit_W, logit_WT, VOUT, 512, 0, 0, 0, 0);
    gemm_bf16<<<dim3(FIVEL / 128, TDEC * BB / 128), blk, 0, stream>>>(
        dec_x_b, WiT_dec, dec_bi, dec_pre_b, FIVEL, EE, FIVEL);

    // ---- decoder scan (2 kernels per step) ----
    const ushort_t* dh = h_enc;
    for (int t = 0; t < TDEC; ++t) {
        attfuse2<<<BB, blk, 0, stream>>>(
            dh, tproj_b, 512, thought_b,
            decWh2aT, dec_bh2a, dec_Watt, attv_b, RSTEPS);
        const float* ci = (t == 0) ? cbuf[0] : cbuf[2 + ((t - 1) & 1)];
        lstm_fused<2><<<32, blk, 0, stream>>>(
            dh, attv_b, decWcomb, 1024,
            dec_pre_b + (size_t)t * 163840,
            dec_bh, dec_ba,
            ci, cbuf[2 + (t & 1)],
            hb[t & 1], dec_h_b + (size_t)t * 32768);
        dh = hb[t & 1];
    }

    // ---- logit GEMM (fused softmax partials) + lse merge/subtract ----
    gemm_logit<<<dim3(235, 25), blk, 0, stream>>>(
        dec_h_b, logit_WT, logit_b, out, part, VOUT, LDIM);
    logsm_sub<<<TDEC * BB, blk, 0, stream>>>(out, part);
}

// Round 10
// 3350.981 us; speedup vs baseline: 1.3173x; 1.3173x over previous
//
#include <hip/hip_runtime.h>
#include <math.h>
#include <stdint.h>

#define BB     64
#define TENC   100
#define TDEC   50
#define LDIM   512
#define EE     512
#define HDIM   512
#define FIVEL  2560
#define RSTEPS 8
#define VOUT   30000
#define NB2    470     // 64-col partial chunks per logit row (470*64 = 30080)

typedef __attribute__((ext_vector_type(8))) short short8v;   // 8 x bf16
typedef __attribute__((ext_vector_type(4))) float floatx4;
typedef unsigned short ushort_t;

// ---------------- workspace offsets (float units) ----------------
static const size_t OFF_A        = 0;
static const size_t OFF_WIT_ENC  = 8192000;
static const size_t OFF_ENCX     = 8847360;    // ends 10,485,760
static const size_t OFF_LOGWT    = 0;
static const size_t OFF_DECH     = 7680000;    // ends 8,499,200
static const size_t OFF_DECPRE   = 8499200;    // ends 12,595,200
static const size_t OFF_ENC_HS   = 13107200;   // 1,638,400 (TPW aliases first 655,360 post-review; h_enc slot 99 untouched)
static const size_t OFF_TPW      = 13107200;
static const size_t OFF_ENC_WHT  = 14745600;   // 655,360
static const size_t OFF_REVWC    = 15400960;   // 10,485,760 (dead post-review)
static const size_t OFF_PART     = 15400960;   // logit partials (aliases REVWC)
static const size_t OFF_DECWC    = 25886720;   // decWhT 655,360 + WaT_dec 655,360
static const size_t OFF_WIT_DEC  = 27197440;   // 655,360
static const size_t OFF_REVWT    = 27852800;   // 1,048,576
static const size_t OFF_DECWT    = 28901376;   // 131,072
static const size_t OFF_REVWH2AT = 29032448;   // 1,048,576
static const size_t OFF_DECWH2AT = 30081024;   // 131,072
static const size_t OFF_DECX     = 30212096;   // 819,200
static const size_t OFF_THOUGHT  = 31031296;   // 131,072
static const size_t OFF_TPROJ    = 31162368;   // 131,072
static const size_t OFF_HB0      = 31293440;   // 16,384
static const size_t OFF_HB1      = 31309824;   // 16,384
static const size_t OFF_ATTV     = 31326208;   // 16,384
static const size_t OFF_H0       = 31342592;   // 16,384
static const size_t OFF_C0       = 31358976;   // 4 x 32,768
static const size_t OFF_SBUF     = 31490048;   // 163,840 (64 x 2560 fp32)
static const size_t OFF_ALPHA    = 31653888;   // 512
static const size_t WS_TOTAL     = 31654400;   // 126.6 MB (< 127.9 proven)

__device__ __forceinline__ float sigmoidf_(float x) { return 1.0f / (1.0f + __expf(-x)); }
__device__ __forceinline__ float tanh_fast(float x) { return 1.0f - 2.0f / (__expf(2.0f * x) + 1.0f); }
__device__ __forceinline__ unsigned short f2bf(float x) {
    unsigned u = __float_as_uint(x);
    u += 0x7FFFu + ((u >> 16) & 1u);
    return (unsigned short)(u >> 16);
}
__device__ __forceinline__ float bf2f(unsigned short h) {
    return __uint_as_float(((unsigned)h) << 16);
}

// ---------------------------------------------------------------------------
__global__ __launch_bounds__(128)
void gather_embed(const float* __restrict__ embed, const int* __restrict__ tok,
                  int T, ushort_t* __restrict__ X)
{
    int m = blockIdx.x, t = m / BB, b = m % BB;
    const float* src = embed + (size_t)tok[b * T + t] * EE;
    float4 v = *(const float4*)(src + threadIdx.x * 4);
    ushort4 o = { f2bf(v.x), f2bf(v.y), f2bf(v.z), f2bf(v.w) };
    *(ushort4*)(X + (size_t)m * EE + threadIdx.x * 4) = o;
}

// ---------------------------------------------------------------------------
__global__ __launch_bounds__(256)
void conv_transpose(const float* __restrict__ W, ushort_t* __restrict__ WT,
                    int N, int ldWT, int kofs, long Wz, long WTz)
{
    W  += (size_t)blockIdx.z * Wz;
    WT += (size_t)blockIdx.z * WTz;
    __shared__ float tile[32][33];
    int n0 = blockIdx.x * 32, k0 = blockIdx.y * 32;
    int tx = threadIdx.x & 31, ty = threadIdx.x >> 5;
    #pragma unroll
    for (int i = 0; i < 4; ++i) {
        int k = k0 + ty + i * 8, n = n0 + tx;
        tile[ty + i * 8][tx] = (n < N) ? W[(size_t)k * N + n] : 0.f;
    }
    __syncthreads();
    #pragma unroll
    for (int i = 0; i < 4; ++i) {
        int n = n0 + ty + i * 8, k = k0 + tx;
        if (n < N) WT[(size_t)n * ldWT + kofs + k] = f2bf(tile[tx][ty + i * 8]);
    }
}

// ---------------------------------------------------------------------------
// bf16 MFMA GEMM, bf16 out, LDS-staged coalesced epilogue (R8-proven).
// ---------------------------------------------------------------------------
__global__ __launch_bounds__(256)
void gemm_bf16(const ushort_t* __restrict__ A, const ushort_t* __restrict__ BT,
               const float* __restrict__ bias, ushort_t* __restrict__ Cb,
               int N, int K, long ldc)
{
    __shared__ ushort_t lds[2][128][32];
    __shared__ ushort_t ctile[128 * 128];
    const int tid  = threadIdx.x;
    const int wave = tid >> 6, lane = tid & 63;
    const int m0 = blockIdx.y * 128, n0 = blockIdx.x * 128;
    const int wr = wave >> 1, wc = wave & 1;

    floatx4 acc[4][4] = {};
    const int sr  = lane >> 2;
    const int scp = lane & 3;

    for (int k0 = 0; k0 < K; k0 += 32) {
        #pragma unroll
        for (int half = 0; half < 2; ++half) {
            int rbase = wave * 32 + half * 16;
            int r = rbase + sr;
            int c = scp ^ ((r >> 1) & 3);
            const ushort_t* ga = A + (size_t)(m0 + r) * K + k0 + c * 8;
            const ushort_t* gb = BT + (size_t)(n0 + r) * K + k0 + c * 8;
            __builtin_amdgcn_global_load_lds(
                (const __attribute__((address_space(1))) void*)ga,
                (__attribute__((address_space(3))) void*)&lds[0][rbase][0], 16, 0, 0);
            __builtin_amdgcn_global_load_lds(
                (const __attribute__((address_space(1))) void*)gb,
                (__attribute__((address_space(3))) void*)&lds[1][rbase][0], 16, 0, 0);
        }
        __syncthreads();

        short8v af[4], bv[4];
        #pragma unroll
        for (int i = 0; i < 4; ++i) {
            int ra = wr * 64 + i * 16 + (lane & 15);
            int ca = (lane >> 4) ^ ((ra >> 1) & 3);
            af[i] = *(const short8v*)&lds[0][ra][ca * 8];
            int rb = wc * 64 + i * 16 + (lane & 15);
            int cb = (lane >> 4) ^ ((rb >> 1) & 3);
            bv[i] = *(const short8v*)&lds[1][rb][cb * 8];
        }
        #pragma unroll
        for (int i = 0; i < 4; ++i)
            #pragma unroll
            for (int j = 0; j < 4; ++j)
                acc[i][j] = __builtin_amdgcn_mfma_f32_16x16x32_bf16(af[i], bv[j], acc[i][j], 0, 0, 0);
        __syncthreads();
    }

    const int crow0 = wr * 64 + (lane >> 4) * 4;
    const int ccol0 = wc * 64 + (lane & 15);
    #pragma unroll
    for (int i = 0; i < 4; ++i) {
        #pragma unroll
        for (int j = 0; j < 4; ++j) {
            int col = ccol0 + j * 16;
            float bval = bias ? bias[n0 + col] : 0.f;
            #pragma unroll
            for (int rr = 0; rr < 4; ++rr)
                ctile[(crow0 + i * 16 + rr) * 128 + col] = f2bf(acc[i][j][rr] + bval);
        }
    }
    __syncthreads();
    #pragma unroll
    for (int itc = 0; itc < 8; ++itc) {
        int chunk = itc * 256 + tid;
        int row = chunk >> 4, ch = chunk & 15;
        *(short8v*)(Cb + (size_t)(m0 + row) * ldc + n0 + ch * 8) =
            *(const short8v*)&ctile[row * 128 + ch * 8];
    }
}

// ---------------------------------------------------------------------------
// Logit GEMM (R8-proven core) with XCD-chunked, M-fast block swizzle so each
// N-slice's B panel is fetched once per XCD and A stays L2-resident.
// ---------------------------------------------------------------------------
__global__ __launch_bounds__(256)
void gemm_logit(const ushort_t* __restrict__ A, const ushort_t* __restrict__ BT,
                const float* __restrict__ bias, float* __restrict__ C,
                float2* __restrict__ part, int N, int K)
{
    __shared__ ushort_t lds[2][128][32];
    __shared__ float ctf[128 * 128];
    const int tid  = threadIdx.x;
    const int wave = tid >> 6, lane = tid & 63;
    // bijective XCD swizzle: nwg = 5875 = 8*734 + 3 (m204 formula), then
    // M-fast within N-slices (25 M-tiles per slice).
    int lin = blockIdx.x;
    int xcd = lin & 7, o = lin >> 3;
    int wgid = (xcd < 3 ? xcd * 735 + o : 3 * 735 + (xcd - 3) * 734 + o);
    const int ntile = wgid / 25, mtile = wgid % 25;
    const int m0 = mtile * 128, n0 = ntile * 128;
    const int wr = wave >> 1, wc = wave & 1;

    floatx4 acc[4][4] = {};
    const int sr  = lane >> 2;
    const int scp = lane & 3;

    for (int k0 = 0; k0 < K; k0 += 32) {
        #pragma unroll
        for (int half = 0; half < 2; ++half) {
            int rbase = wave * 32 + half * 16;
            int r = rbase + sr;
            int c = scp ^ ((r >> 1) & 3);
            const ushort_t* ga = A + (size_t)(m0 + r) * K + k0 + c * 8;
            int nr = n0 + r; if (nr >= N) nr = 0;
            const ushort_t* gb = BT + (size_t)nr * K + k0 + c * 8;
            __builtin_amdgcn_global_load_lds(
                (const __attribute__((address_space(1))) void*)ga,
                (__attribute__((address_space(3))) void*)&lds[0][rbase][0], 16, 0, 0);
            __builtin_amdgcn_global_load_lds(
                (const __attribute__((address_space(1))) void*)gb,
                (__attribute__((address_space(3))) void*)&lds[1][rbase][0], 16, 0, 0);
        }
        __syncthreads();

        short8v af[4], bv[4];
        #pragma unroll
        for (int i = 0; i < 4; ++i) {
            int ra = wr * 64 + i * 16 + (lane & 15);
            int ca = (lane >> 4) ^ ((ra >> 1) & 3);
            af[i] = *(const short8v*)&lds[0][ra][ca * 8];
            int rb = wc * 64 + i * 16 + (lane & 15);
            int cb = (lane >> 4) ^ ((rb >> 1) & 3);
            bv[i] = *(const short8v*)&lds[1][rb][cb * 8];
        }
        #pragma unroll
        for (int i = 0; i < 4; ++i)
            #pragma unroll
            for (int j = 0; j < 4; ++j)
                acc[i][j] = __builtin_amdgcn_mfma_f32_16x16x32_bf16(af[i], bv[j], acc[i][j], 0, 0, 0);
        __syncthreads();
    }

    const int cn = lane & 15, qq = lane >> 4;
    const int lcol0 = wc * 64 + cn;
    float bv[4]; bool valid[4];
    #pragma unroll
    for (int j = 0; j < 4; ++j) {
        int col = n0 + lcol0 + j * 16;
        valid[j] = col < N;
        bv[j] = valid[j] ? bias[col] : 0.f;
    }
    const int nb2 = ntile * 2 + wc;
    #pragma unroll
    for (int i = 0; i < 4; ++i) {
        #pragma unroll
        for (int rr = 0; rr < 4; ++rr) {
            int lrow = wr * 64 + qq * 4 + i * 16 + rr;
            int m = m0 + lrow;
            float v[4];
            #pragma unroll
            for (int j = 0; j < 4; ++j)
                v[j] = valid[j] ? acc[i][j][rr] + bv[j] : -3.0e38f;
            float mx = fmaxf(fmaxf(v[0], v[1]), fmaxf(v[2], v[3]));
            #pragma unroll
            for (int msk = 1; msk < 16; msk <<= 1) mx = fmaxf(mx, __shfl_xor(mx, msk));
            float sm = 0.f;
            #pragma unroll
            for (int j = 0; j < 4; ++j) if (valid[j]) sm += __expf(v[j] - mx);
            #pragma unroll
            for (int msk = 1; msk < 16; msk <<= 1) sm += __shfl_xor(sm, msk);
            if (cn == 0) part[(size_t)m * NB2 + nb2] = make_float2(mx, sm);
            #pragma unroll
            for (int j = 0; j < 4; ++j)
                ctf[lrow * 128 + lcol0 + j * 16] = v[j];
        }
    }
    __syncthreads();
    #pragma unroll
    for (int itc = 0; itc < 16; ++itc) {
        int chunk = itc * 256 + tid;
        int row = chunk >> 5, ch = chunk & 31;
        int col = n0 + ch * 4;
        if (col < N) {
            int m = m0 + row;
            int t = m >> 6, bb = m & 63;
            float* dst = C + ((size_t)bb * TDEC + t) * VOUT + col;
            if (col + 3 < N) {
                *(floatx4*)dst = *(const floatx4*)&ctf[row * 128 + ch * 4];
            } else {
                for (int e = 0; e < 4 && col + e < N; ++e)
                    dst[e] = ctf[row * 128 + ch * 4 + e];
            }
        }
    }
}

// ---------------------------------------------------------------------------
__global__ __launch_bounds__(256)
void logsm_sub(float* __restrict__ out, const float2* __restrict__ part)
{
    const int r = blockIdx.x;
    const int b = r / TDEC, t = r % TDEC;
    const int m = t * 64 + b;
    const int tid = threadIdx.x, wave = tid >> 6, lane = tid & 63;
    float M = -3.0e38f, S = 0.f;
    for (int i = tid; i < NB2; i += 256) {
        float2 p = part[(size_t)m * NB2 + i];
        float nm = fmaxf(M, p.x);
        S = S * __expf(M - nm) + p.y * __expf(p.x - nm);
        M = nm;
    }
    #pragma unroll
    for (int off = 32; off; off >>= 1) {
        float Mo = __shfl_xor(M, off), So = __shfl_xor(S, off);
        float nm = fmaxf(M, Mo);
        S = S * __expf(M - nm) + So * __expf(Mo - nm);
        M = nm;
    }
    __shared__ float ms[4], ss[4];
    if (lane == 0) { ms[wave] = M; ss[wave] = S; }
    __syncthreads();
    float M2 = fmaxf(fmaxf(ms[0], ms[1]), fmaxf(ms[2], ms[3]));
    float S2 = ss[0] * __expf(ms[0] - M2) + ss[1] * __expf(ms[1] - M2) +
               ss[2] * __expf(ms[2] - M2) + ss[3] * __expf(ms[3] - M2);
    float lse = M2 + __logf(S2);
    floatx4* row = (floatx4*)(out + (size_t)r * VOUT);
    for (int i = tid; i < VOUT / 4; i += 256) {
        floatx4 x = __builtin_nontemporal_load(row + i);
        x[0] -= lse; x[1] -= lse; x[2] -= lse; x[3] -= lse;
        __builtin_nontemporal_store(x, row + i);
    }
}

// ---------------------------------------------------------------------------
// Step GEMM phase A (R8-proven): s[64][2560] = [a0|a1] @ BT^T. 160 blocks.
// ---------------------------------------------------------------------------
template<int NSEG>
__global__ __launch_bounds__(256)
void step_gemm(const ushort_t* __restrict__ a0, const ushort_t* __restrict__ a1,
               const ushort_t* __restrict__ BT, int ldBT, float* __restrict__ sbuf)
{
    constexpr int K = NSEG * 512;
    constexpr int LROW = K + 8;
    __shared__ ushort_t Bl[16 * LROW];
    const int tid = threadIdx.x, wave = tid >> 6, lane = tid & 63;
    const int q = lane >> 4, cn = lane & 15;
    const int n0 = blockIdx.x * 16;

    #pragma unroll
    for (int it = 0; it < NSEG * 4; ++it) {
        int slot = it * 4 + wave;
        int row  = slot / NSEG;
        int part = slot % NSEG;
        const ushort_t* src = BT + (size_t)(n0 + row) * ldBT + part * 512 + lane * 8;
        __builtin_amdgcn_global_load_lds(
            (const __attribute__((address_space(1))) void*)src,
            (__attribute__((address_space(3))) void*)&Bl[row * LROW + part * 512], 16, 0, 0);
    }
    __syncthreads();

    floatx4 acc = {0.f, 0.f, 0.f, 0.f};
    {
        const ushort_t* Ap = a0 + (size_t)(wave * 16 + cn) * 512 + q * 8;
        #pragma unroll
        for (int kt = 0; kt < 16; ++kt) {
            short8v af = *(const short8v*)(Ap + kt * 32);
            short8v bf = *(const short8v*)&Bl[cn * LROW + kt * 32 + q * 8];
            acc = __builtin_amdgcn_mfma_f32_16x16x32_bf16(af, bf, acc, 0, 0, 0);
        }
    }
    if (NSEG == 2) {
        const ushort_t* Ap = a1 + (size_t)(wave * 16 + cn) * 512 + q * 8;
        #pragma unroll
        for (int kt = 0; kt < 16; ++kt) {
            short8v af = *(const short8v*)(Ap + kt * 32);
            short8v bf = *(const short8v*)&Bl[cn * LROW + 512 + kt * 32 + q * 8];
            acc = __builtin_amdgcn_mfma_f32_16x16x32_bf16(af, bf, acc, 0, 0, 0);
        }
    }
    #pragma unroll
    for (int rr = 0; rr < 4; ++rr)
        sbuf[(size_t)(wave * 16 + q * 4 + rr) * FIVEL + n0 + cn] = acc[rr];
}

// ---------------------------------------------------------------------------
// Step phase B for encoder (R8-proven): maxout-LSTM epilogue. 64 blocks.
// ---------------------------------------------------------------------------
__global__ __launch_bounds__(256)
void lstm_epi(const float* __restrict__ s, const ushort_t* __restrict__ pre,
              const float* __restrict__ b0, const float* __restrict__ b1,
              const float* __restrict__ c_in, float* __restrict__ c_out,
              ushort_t* __restrict__ h_out, ushort_t* __restrict__ h_copy)
{
    int idx = blockIdx.x * 256 + threadIdx.x;
    int row = idx >> 8;
    int c   = (idx & 255) * 2;
    float sg[5][2];
    #pragma unroll
    for (int g = 0; g < 5; ++g) {
        float2 v = *(const float2*)(s + (size_t)row * FIVEL + g * 512 + c);
        sg[g][0] = v.x + b0[g * 512 + c];
        sg[g][1] = v.y + b0[g * 512 + c + 1];
        if (b1) {
            sg[g][0] += b1[g * 512 + c];
            sg[g][1] += b1[g * 512 + c + 1];
        }
        if (pre) {
            ushort2 p = *(const ushort2*)(pre + (size_t)row * FIVEL + g * 512 + c);
            sg[g][0] += bf2f(p.x);
            sg[g][1] += bf2f(p.y);
        }
    }
    float2 ci = *(const float2*)(c_in + (size_t)row * 512 + c);
    float cc[2] = {ci.x, ci.y};
    ushort_t hh[2];
    #pragma unroll
    for (int e = 0; e < 2; ++e) {
        float ig = sigmoidf_(sg[0][e]), fg = sigmoidf_(sg[1][e]), og = sigmoidf_(sg[2][e]);
        float tt = fmaxf(sg[3][e], sg[4][e]);
        float c2 = fg * cc[e] + ig * tt;
        cc[e] = c2;
        hh[e] = f2bf(og * tanh_fast(c2));
    }
    *(float2*)(c_out + (size_t)row * 512 + c) = make_float2(cc[0], cc[1]);
    ushort2 ho = {hh[0], hh[1]};
    *(ushort2*)(h_out + (size_t)row * 512 + c) = ho;
    if (h_copy) *(ushort2*)(h_copy + (size_t)row * 512 + c) = ho;
}

// ---------------------------------------------------------------------------
// Fused epilogue + next-step attention. Block = batch b, 64 blocks.
// EPI (if s): gates from s (+pre/+b1/+Σalpha*TPW) -> h (LDS + global), c.
// ATT (if W2aT): hproj MFMA from LDS h -> scores vs projBase -> softmax ->
//   attv_out (full, A up to 128) or alphas_out (A floats per b).
// ---------------------------------------------------------------------------
__global__ __launch_bounds__(256)
void epi_att(const float* __restrict__ s, const ushort_t* __restrict__ hprev,
             const ushort_t* __restrict__ pre,
             const float* __restrict__ b0, const float* __restrict__ b1,
             const ushort_t* __restrict__ tpw, const float* __restrict__ alpha_in,
             const float* __restrict__ c_in, float* __restrict__ c_out,
             ushort_t* __restrict__ h_out, ushort_t* __restrict__ h_copy,
             const ushort_t* __restrict__ projBase, long projLd,
             const ushort_t* __restrict__ feats,
             const ushort_t* __restrict__ W2aT, const float* __restrict__ b2a,
             const float* __restrict__ Watt,
             ushort_t* __restrict__ attv_out, float* __restrict__ alphas_out, int A)
{
    __shared__ ushort_t hl[512];
    __shared__ float hp[512];
    __shared__ float ealpha[128];
    const int b = blockIdx.x;
    const int tid = threadIdx.x, wave = tid >> 6, lane = tid & 63;

    if (s) {
        const int c = tid * 2;
        float al[8];
        if (tpw) {
            #pragma unroll
            for (int a = 0; a < 8; ++a) al[a] = alpha_in[b * 8 + a];
        }
        float sg[5][2];
        #pragma unroll
        for (int g = 0; g < 5; ++g) {
            float2 v = *(const float2*)(s + (size_t)b * FIVEL + g * 512 + c);
            sg[g][0] = v.x + b0[g * 512 + c];
            sg[g][1] = v.y + b0[g * 512 + c + 1];
            if (b1) {
                sg[g][0] += b1[g * 512 + c];
                sg[g][1] += b1[g * 512 + c + 1];
            }
            if (pre) {
                ushort2 p = *(const ushort2*)(pre + (size_t)b * FIVEL + g * 512 + c);
                sg[g][0] += bf2f(p.x);
                sg[g][1] += bf2f(p.y);
            }
            if (tpw) {
                #pragma unroll
                for (int a = 0; a < 8; ++a) {
                    ushort2 tv = *(const ushort2*)(tpw + ((size_t)a * 64 + b) * FIVEL + g * 512 + c);
                    sg[g][0] += al[a] * bf2f(tv.x);
                    sg[g][1] += al[a] * bf2f(tv.y);
                }
            }
        }
        float2 ci = *(const float2*)(c_in + (size_t)b * 512 + c);
        float cc[2] = {ci.x, ci.y};
        ushort_t hh[2];
        #pragma unroll
        for (int e = 0; e < 2; ++e) {
            float ig = sigmoidf_(sg[0][e]), fg = sigmoidf_(sg[1][e]), og = sigmoidf_(sg[2][e]);
            float tt = fmaxf(sg[3][e], sg[4][e]);
            float c2 = fg * cc[e] + ig * tt;
            cc[e] = c2;
            hh[e] = f2bf(og * tanh_fast(c2));
        }
        *(float2*)(c_out + (size_t)b * 512 + c) = make_float2(cc[0], cc[1]);
        ushort2 ho = {hh[0], hh[1]};
        *(ushort2*)(h_out + (size_t)b * 512 + c) = ho;
        if (h_copy) *(ushort2*)(h_copy + (size_t)b * 512 + c) = ho;
        *(ushort2*)&hl[c] = ho;
    } else {
        *(ushort2*)&hl[tid * 2] = *(const ushort2*)(hprev + (size_t)b * 512 + tid * 2);
    }
    if (!W2aT) return;
    __syncthreads();

    // hproj via MFMA (A-frag broadcast from LDS h)
    const int q = lane >> 4, cn = lane & 15;
    floatx4 acc[8] = {};
    {
        const ushort_t* Bp = W2aT + (size_t)(wave * 128 + cn) * 512 + q * 8;
        #pragma unroll 2
        for (int kt = 0; kt < 16; ++kt) {
            short8v af = *(const short8v*)&hl[kt * 32 + q * 8];
            #pragma unroll
            for (int t8 = 0; t8 < 8; ++t8) {
                short8v bf = *(const short8v*)(Bp + (size_t)t8 * 16 * 512 + kt * 32);
                acc[t8] = __builtin_amdgcn_mfma_f32_16x16x32_bf16(af, bf, acc[t8], 0, 0, 0);
            }
        }
    }
    if (q == 0) {
        #pragma unroll
        for (int t8 = 0; t8 < 8; ++t8) {
            int n = wave * 128 + t8 * 16 + cn;
            hp[n] = acc[t8][0] + b2a[n];
        }
    }
    __syncthreads();

    float hpr[8], war[8];
    {
        float4 w0 = *(const float4*)(Watt + lane * 8);
        float4 w1 = *(const float4*)(Watt + lane * 8 + 4);
        war[0] = w0.x; war[1] = w0.y; war[2] = w0.z; war[3] = w0.w;
        war[4] = w1.x; war[5] = w1.y; war[6] = w1.z; war[7] = w1.w;
        #pragma unroll
        for (int j = 0; j < 8; ++j) hpr[j] = hp[lane * 8 + j];
    }

    for (int a = wave; a < A; a += 4) {
        short8v pv = *(const short8v*)(projBase + ((size_t)a * 64 + b) * projLd + lane * 8);
        float e = 0.f;
        #pragma unroll
        for (int j = 0; j < 8; ++j)
            e += tanh_fast(bf2f((ushort_t)pv[j]) + hpr[j]) * war[j];
        #pragma unroll
        for (int off = 32; off; off >>= 1) e += __shfl_xor(e, off);
        if (lane == 0) ealpha[a] = e;
    }
    __syncthreads();
    if (wave == 0) {
        float v1 = (lane < A) ? ealpha[lane] : -3.0e38f;
        float v2 = (lane + 64 < A) ? ealpha[lane + 64] : -3.0e38f;
        float mm = fmaxf(v1, v2);
        #pragma unroll
        for (int off = 32; off; off >>= 1) mm = fmaxf(mm, __shfl_xor(mm, off));
        float x1 = (lane < A) ? __expf(v1 - mm) : 0.f;
        float x2 = (lane + 64 < A) ? __expf(v2 - mm) : 0.f;
        float ss = x1 + x2;
        #pragma unroll
        for (int off = 32; off; off >>= 1) ss += __shfl_xor(ss, off);
        float inv = 1.f / ss;
        if (lane < A) ealpha[lane] = x1 * inv;
        if (lane + 64 < A) ealpha[lane + 64] = x2 * inv;
    }
    __syncthreads();

    if (attv_out) {
        float s0 = 0.f, s1 = 0.f;
        for (int a = 0; a < A; ++a) {
            float alv = ealpha[a];
            unsigned int u = *(const unsigned int*)(feats + ((size_t)a * 64 + b) * 512 + tid * 2);
            s0 += alv * bf2f((ushort_t)(u & 0xffffu));
            s1 += alv * bf2f((ushort_t)(u >> 16));
        }
        ushort2 o = { f2bf(s0), f2bf(s1) };
        *(ushort2*)(attv_out + (size_t)b * 512 + tid * 2) = o;
    } else {
        if (tid < A) alphas_out[b * A + tid] = ealpha[tid];
    }
}

// ---------------------------------------------------------------------------
// Standalone attention (R8-proven) for the review r=0 bootstrap.
// ---------------------------------------------------------------------------
__global__ __launch_bounds__(256)
void attfuse2(const ushort_t* __restrict__ hprev,
              const ushort_t* __restrict__ projBase, long projLd,
              const ushort_t* __restrict__ feats,
              const ushort_t* __restrict__ W2aT, const float* __restrict__ b2a,
              const float* __restrict__ Watt, ushort_t* __restrict__ attv, int A)
{
    __shared__ float hp[512];
    __shared__ float ealpha[128];
    const int b = blockIdx.x;
    const int tid = threadIdx.x, wave = tid >> 6, lane = tid & 63;
    const int q = lane >> 4, cn = lane & 15;

    floatx4 acc[8] = {};
    {
        const ushort_t* Ap = hprev + (size_t)b * 512 + q * 8;
        const ushort_t* Bp = W2aT + (size_t)(wave * 128 + cn) * 512 + q * 8;
        #pragma unroll 2
        for (int kt = 0; kt < 16; ++kt) {
            short8v af = *(const short8v*)(Ap + kt * 32);
            #pragma unroll
            for (int t8 = 0; t8 < 8; ++t8) {
                short8v bf = *(const short8v*)(Bp + (size_t)t8 * 16 * 512 + kt * 32);
                acc[t8] = __builtin_amdgcn_mfma_f32_16x16x32_bf16(af, bf, acc[t8], 0, 0, 0);
            }
        }
    }
    if (q == 0) {
        #pragma unroll
        for (int t8 = 0; t8 < 8; ++t8) {
            int n = wave * 128 + t8 * 16 + cn;
            hp[n] = acc[t8][0] + b2a[n];
        }
    }
    __syncthreads();

    float hpr[8], war[8];
    {
        float4 w0 = *(const float4*)(Watt + lane * 8);
        float4 w1 = *(const float4*)(Watt + lane * 8 + 4);
        war[0] = w0.x; war[1] = w0.y; war[2] = w0.z; war[3] = w0.w;
        war[4] = w1.x; war[5] = w1.y; war[6] = w1.z; war[7] = w1.w;
        #pragma unroll
        for (int j = 0; j < 8; ++j) hpr[j] = hp[lane * 8 + j];
    }

    for (int a = wave; a < A; a += 4) {
        short8v pv = *(const short8v*)(projBase + ((size_t)a * 64 + b) * projLd + lane * 8);
        float e = 0.f;
        #pragma unroll
        for (int j = 0; j < 8; ++j)
            e += tanh_fast(bf2f((ushort_t)pv[j]) + hpr[j]) * war[j];
        #pragma unroll
        for (int off = 32; off; off >>= 1) e += __shfl_xor(e, off);
        if (lane == 0) ealpha[a] = e;
    }
    __syncthreads();
    if (wave == 0) {
        float v1 = (lane < A) ? ealpha[lane] : -3.0e38f;
        float v2 = (lane + 64 < A) ? ealpha[lane + 64] : -3.0e38f;
        float mm = fmaxf(v1, v2);
        #pragma unroll
        for (int off = 32; off; off >>= 1) mm = fmaxf(mm, __shfl_xor(mm, off));
        float x1 = (lane < A) ? __expf(v1 - mm) : 0.f;
        float x2 = (lane + 64 < A) ? __expf(v2 - mm) : 0.f;
        float ss = x1 + x2;
        #pragma unroll
        for (int off = 32; off; off >>= 1) ss += __shfl_xor(ss, off);
        float inv = 1.f / ss;
        if (lane < A) ealpha[lane] = x1 * inv;
        if (lane + 64 < A) ealpha[lane + 64] = x2 * inv;
    }
    __syncthreads();

    float s0 = 0.f, s1 = 0.f;
    for (int a = 0; a < A; ++a) {
        float al = ealpha[a];
        unsigned int u = *(const unsigned int*)(feats + ((size_t)a * 64 + b) * 512 + tid * 2);
        s0 += al * bf2f((ushort_t)(u & 0xffffu));
        s1 += al * bf2f((ushort_t)(u >> 16));
    }
    ushort2 o = { f2bf(s0), f2bf(s1) };
    *(ushort2*)(attv + (size_t)b * 512 + tid * 2) = o;
}

// ---------------------------------------------------------------------------
extern "C" void kernel_launch(void* const* d_in, const int* in_sizes, int n_in,
                              void* d_out_, int out_size, void* d_ws, size_t ws_size,
                              hipStream_t stream)
{
    const int*   code     = (const int*)  d_in[0];
    const int*   comment  = (const int*)  d_in[1];
    const float* embed    = (const float*)d_in[3];
    const float* enc_Wi   = (const float*)d_in[4];
    const float* enc_bi   = (const float*)d_in[5];
    const float* enc_Wh   = (const float*)d_in[6];
    const float* enc_bh   = (const float*)d_in[7];
    const float* rev_Wh   = (const float*)d_in[8];
    const float* rev_bh   = (const float*)d_in[9];
    const float* rev_Wa   = (const float*)d_in[10];
    const float* rev_ba   = (const float*)d_in[11];
    const float* rev_Wa2a = (const float*)d_in[12];
    const float* rev_ba2a = (const float*)d_in[13];
    const float* rev_Wh2a = (const float*)d_in[14];
    const float* rev_bh2a = (const float*)d_in[15];
    const float* rev_Watt = (const float*)d_in[16];
    const float* dec_Wi   = (const float*)d_in[18];
    const float* dec_bi   = (const float*)d_in[19];
    const float* dec_Wh   = (const float*)d_in[20];
    const float* dec_bh   = (const float*)d_in[21];
    const float* dec_Wa   = (const float*)d_in[22];
    const float* dec_ba   = (const float*)d_in[23];
    const float* dec_Wa2a = (const float*)d_in[24];
    const float* dec_ba2a = (const float*)d_in[25];
    const float* dec_Wh2a = (const float*)d_in[26];
    const float* dec_bh2a = (const float*)d_in[27];
    const float* dec_Watt = (const float*)d_in[28];
    const float* logit_W  = (const float*)d_in[30];
    const float* logit_b  = (const float*)d_in[31];
    float* out = (float*)d_out_;

    float* ws = (float*)d_ws;
    if (ws_size < WS_TOTAL * sizeof(float)) return;

    ushort_t* enc_pre_b = (ushort_t*)(ws + OFF_A);
    ushort_t* rev_projA = (ushort_t*)(ws + OFF_A);
    ushort_t* logit_WT  = (ushort_t*)(ws + OFF_LOGWT);
    ushort_t* dec_h_b   = (ushort_t*)(ws + OFF_DECH);
    ushort_t* dec_pre_b = (ushort_t*)(ws + OFF_DECPRE);
    ushort_t* WiT_enc   = (ushort_t*)(ws + OFF_WIT_ENC);
    ushort_t* enc_x_b   = (ushort_t*)(ws + OFF_ENCX);
    ushort_t* enc_hs_b  = (ushort_t*)(ws + OFF_ENC_HS);
    ushort_t* TPW       = (ushort_t*)(ws + OFF_TPW);     // aliases enc_hs slots 0..40
    ushort_t* encWhT    = (ushort_t*)(ws + OFF_ENC_WHT);
    ushort_t* revWcomb  = (ushort_t*)(ws + OFF_REVWC);
    float2*   part      = (float2*)(ws + OFF_PART);
    ushort_t* decWhT    = (ushort_t*)(ws + OFF_DECWC);
    ushort_t* WaT_dec   = (ushort_t*)(ws + OFF_DECWC + 655360);
    ushort_t* WiT_dec   = (ushort_t*)(ws + OFF_WIT_DEC);
    ushort_t* revWT     = (ushort_t*)(ws + OFF_REVWT);
    ushort_t* decWT     = (ushort_t*)(ws + OFF_DECWT);
    ushort_t* revWh2aT  = (ushort_t*)(ws + OFF_REVWH2AT);
    ushort_t* decWh2aT  = (ushort_t*)(ws + OFF_DECWH2AT);
    ushort_t* dec_x_b   = (ushort_t*)(ws + OFF_DECX);
    ushort_t* thought_b = (ushort_t*)(ws + OFF_THOUGHT);
    ushort_t* tproj_b   = (ushort_t*)(ws + OFF_TPROJ);
    ushort_t* hb[2] = { (ushort_t*)(ws + OFF_HB0), (ushort_t*)(ws + OFF_HB1) };
    ushort_t* attv_b    = (ushort_t*)(ws + OFF_ATTV);
    ushort_t* h0_b      = (ushort_t*)(ws + OFF_H0);
    float*    sbuf      = ws + OFF_SBUF;
    float*    alphas    = ws + OFF_ALPHA;
    float* cbuf[4];
    for (int i = 0; i < 4; ++i) cbuf[i] = ws + OFF_C0 + (size_t)i * 32768;

    const dim3 blk(256);

    (void)hipMemsetAsync(cbuf[0], 0, (size_t)BB * LDIM * sizeof(float), stream);
    (void)hipMemsetAsync(h0_b, 0, (size_t)BB * LDIM * sizeof(ushort_t), stream);

    // ---- prep: gathers + weight transposes (fp32 -> bf16 [N][K]) ----
    gather_embed<<<TENC * BB, 128, 0, stream>>>(embed, code, TENC, enc_x_b);
    gather_embed<<<TDEC * BB, 128, 0, stream>>>(embed, comment, TDEC, dec_x_b);
    conv_transpose<<<dim3(80, 16, 1), blk, 0, stream>>>(enc_Wi, WiT_enc, FIVEL, 512, 0, 0, 0);
    conv_transpose<<<dim3(80, 16, 1), blk, 0, stream>>>(enc_Wh, encWhT, FIVEL, 512, 0, 0, 0);
    conv_transpose<<<dim3(80, 16, 8), blk, 0, stream>>>(rev_Wh, revWcomb, FIVEL, 1024, 0,   1310720, 2621440);
    conv_transpose<<<dim3(80, 16, 8), blk, 0, stream>>>(rev_Wa, revWcomb, FIVEL, 1024, 512, 1310720, 2621440);
    conv_transpose<<<dim3(16, 16, 8), blk, 0, stream>>>(rev_Wa2a, revWT, 512, 512, 0,       262144, 262144);
    conv_transpose<<<dim3(16, 16, 8), blk, 0, stream>>>(rev_Wh2a, revWh2aT, 512, 512, 0,    262144, 262144);
    conv_transpose<<<dim3(80, 16, 1), blk, 0, stream>>>(dec_Wi, WiT_dec, FIVEL, 512, 0, 0, 0);
    conv_transpose<<<dim3(80, 16, 1), blk, 0, stream>>>(dec_Wh, decWhT, FIVEL, 512, 0, 0, 0);
    conv_transpose<<<dim3(80, 16, 1), blk, 0, stream>>>(dec_Wa, WaT_dec, FIVEL, 512, 0, 0, 0);
    conv_transpose<<<dim3(16, 16, 1), blk, 0, stream>>>(dec_Wa2a, decWT, 512, 512, 0, 0, 0);
    conv_transpose<<<dim3(16, 16, 1), blk, 0, stream>>>(dec_Wh2a, decWh2aT, 512, 512, 0, 0, 0);

    // ---- hoisted encoder input GEMM: enc_pre = enc_x @ Wi + bi ----
    gemm_bf16<<<dim3(FIVEL / 128, TENC * BB / 128), blk, 0, stream>>>(
        enc_x_b, WiT_enc, enc_bi, enc_pre_b, FIVEL, EE, FIVEL);

    // ---- encoder scan (two-phase per step, R8-proven) ----
    for (int t = 0; t < TENC; ++t) {
        const ushort_t* hin = (t == 0) ? h0_b : enc_hs_b + (size_t)(t - 1) * 32768;
        step_gemm<1><<<160, blk, 0, stream>>>(hin, nullptr, encWhT, 512, sbuf);
        lstm_epi<<<64, blk, 0, stream>>>(
            sbuf, enc_pre_b + (size_t)t * 163840, enc_bh, nullptr,
            cbuf[t & 1], cbuf[(t + 1) & 1],
            enc_hs_b + (size_t)t * 32768, nullptr);
    }
    const ushort_t* h_enc = enc_hs_b + (size_t)(TENC - 1) * 32768;
    // c_enc = cbuf[0] (TENC = 100 even)

    // ---- hoisted review projections: rev_projA[m][r*512+n] ----
    gemm_bf16<<<dim3(32, 50), blk, 0, stream>>>(
        enc_hs_b, revWT, rev_ba2a, rev_projA, 4096, LDIM, 4096);

    // ---- review scan: bootstrap attv(0), then {step_gemm, epi_att} ----
    attfuse2<<<BB, blk, 0, stream>>>(
        h_enc, rev_projA, 4096, enc_hs_b,
        revWh2aT, rev_bh2a, rev_Watt, attv_b, TENC);
    const ushort_t* rh = h_enc;
    for (int r = 0; r < RSTEPS; ++r) {
        step_gemm<2><<<160, blk, 0, stream>>>(
            rh, attv_b, revWcomb + (size_t)r * 2621440, 1024, sbuf);
        const float* ci = (r == 0) ? cbuf[0] : cbuf[2 + ((r - 1) & 1)];
        const ushort_t* nextW = (r < RSTEPS - 1) ? revWh2aT + (size_t)(r + 1) * 262144 : nullptr;
        epi_att<<<BB, blk, 0, stream>>>(
            sbuf, nullptr, nullptr,
            rev_bh + (size_t)r * FIVEL, rev_ba + (size_t)r * FIVEL,
            nullptr, nullptr,
            ci, cbuf[2 + (r & 1)],
            hb[r & 1], thought_b + (size_t)r * 32768,
            rev_projA + (size_t)(r + 1) * 512, 4096, enc_hs_b,
            nextW, rev_bh2a + (size_t)(r + 1) * 512, rev_Watt + (size_t)(r + 1) * 512,
            attv_b, nullptr, TENC);
        rh = hb[r & 1];
    }

    // ---- tproj + logit_WT + dec_pre + TPW (rev regions now dead) ----
    gemm_bf16<<<dim3(4, 4), blk, 0, stream>>>(
        thought_b, decWT, dec_ba2a, tproj_b, HDIM, LDIM, HDIM);
    conv_transpose<<<dim3((VOUT + 31) / 32, 16, 1), blk, 0, stream>>>(
        logit_W, logit_WT, VOUT, 512, 0, 0, 0);
    gemm_bf16<<<dim3(FIVEL / 128, TDEC * BB / 128), blk, 0, stream>>>(
        dec_x_b, WiT_dec, dec_bi, dec_pre_b, FIVEL, EE, FIVEL);
    gemm_bf16<<<dim3(20, 4), blk, 0, stream>>>(
        thought_b, WaT_dec, nullptr, TPW, FIVEL, LDIM, FIVEL);

    // ---- decoder scan: bootstrap alpha(0), then {step_gemm<1>, epi_att} ----
    epi_att<<<BB, blk, 0, stream>>>(
        nullptr, h_enc, nullptr, nullptr, nullptr, nullptr, nullptr,
        nullptr, nullptr, nullptr, nullptr,
        tproj_b, 512, nullptr,
        decWh2aT, dec_bh2a, dec_Watt, nullptr, alphas, RSTEPS);
    for (int t = 0; t < TDEC; ++t) {
        const ushort_t* dh = (t == 0) ? h_enc : hb[(t - 1) & 1];
        step_gemm<1><<<160, blk, 0, stream>>>(dh, nullptr, decWhT, 512, sbuf);
        const float* ci = (t == 0) ? cbuf[0] : cbuf[2 + ((t - 1) & 1)];
        const ushort_t* nextW = (t < TDEC - 1) ? decWh2aT : nullptr;
        epi_att<<<BB, blk, 0, stream>>>(
            sbuf, nullptr, dec_pre_b + (size_t)t * 163840,
            dec_bh, dec_ba,
            TPW, alphas,
            ci, cbuf[2 + (t & 1)],
            hb[t & 1], dec_h_b + (size_t)t * 32768,
            tproj_b, 512, nullptr,
            nextW, dec_bh2a, dec_Watt, nullptr, alphas, RSTEPS);
    }

    // ---- logit GEMM (XCD-swizzled, fused softmax partials) + lse pass ----
    gemm_logit<<<dim3(235 * 25), blk, 0, stream>>>(
        dec_h_b, logit_WT, logit_b, out, part, VOUT, LDIM);
    logsm_sub<<<TDEC * BB, blk, 0, stream>>>(out, part);
}